// Round 13
// baseline (408.250 us; speedup 1.0000x reference)
//
#include <hip/hip_runtime.h>
#include <hip/hip_bf16.h>
#include <math.h>

// ---------------------------------------------------------------------------
// DriverGeneGNN: 2-slice GCN (64->64->128) + BN + residual + MLP head.
// N=50000, E=1600000. fp32 accumulate, bf16 operands + bf16 intermediates.
// R13: gather fused into the MFMA GEMMs (gg_kernel): per 64-node tile the 4
//      waves gather 16 nodes each (8 lanes/node, per-edge dinv[src] weight,
//      fp32 accum) -> pack bf16 A-tile in LDS (stride 36 u32) -> de-staged
//      MFMA vs L2-resident packed W^T -> bf16 out + fused BN stats.
//      Eliminates Gb round-trips, prescale/h1sb (gather-0 reads one shared
//      unscaled xb table, 6.4MB), and bnfinal (folded into apply prologues
//      from the 8-way replicated sums). 14 -> 9 dispatches.
// CSR build (R12): kC bins into fixed-stride bucket segments, kB scan, kD.
// MFMA frag layouts (HW-verified): A[m=lane&15][k=(lane>>4)*8+j],
//     B[k][n=lane&15], C/D col=lane&15 row=(lane>>4)*4+reg.
// Conv biases cancel in BN -> skipped.
// ---------------------------------------------------------------------------

typedef short v8s __attribute__((ext_vector_type(8)));
typedef float f32x4 __attribute__((ext_vector_type(4)));

#define BSTRIDE 10240  // u32 slots per 256-col bucket segment (mean 8184)

__device__ __forceinline__ float sanf(float v) {
    if (v != v) return 0.f;
    if (isinf(v)) return v > 0.f ? 100.f : -100.f;
    return v;
}

__device__ __forceinline__ unsigned short bf16of(float v) {
    __hip_bfloat16 h = __float2bfloat16(v);
    return *(unsigned short*)&h;
}
__device__ __forceinline__ unsigned pack2(float lo, float hi) {
    return (unsigned)bf16of(lo) | ((unsigned)bf16of(hi) << 16);
}
__device__ __forceinline__ float uflo(unsigned u) { return __uint_as_float(u << 16); }
__device__ __forceinline__ float ufhi(unsigned u) { return __uint_as_float(u & 0xFFFF0000u); }
__device__ __forceinline__ float fofbf16(unsigned short u) {
    return __uint_as_float(((unsigned)u) << 16);
}

// --- prep: pack weights (W^T bf16-pairs), zero bcnt/sums, xb = bf16(x) ------
// wpk u32 layout: w0T_s0@0(2048) w0T_s1@2048 w1T_s0@4096(4096) w1T_s1@8192
//                 resT_s0@12288 resT_s1@16384 fc1T@20480(16384)  end 36864
__device__ __forceinline__ void packone(const float* __restrict__ src, unsigned* __restrict__ dst,
                                        int L, int Khalf, int F) {
    int c = L / Khalf, kp = L - c * Khalf;
    dst[L] = pack2(src[(2 * kp) * F + c], src[(2 * kp + 1) * F + c]);
}

__global__ __launch_bounds__(256) void prep_kernel(const float* __restrict__ w0_0,
                                                   const float* __restrict__ w0_1,
                                                   const float* __restrict__ w1_0,
                                                   const float* __restrict__ w1_1,
                                                   const float* __restrict__ r_0,
                                                   const float* __restrict__ r_1,
                                                   const float* __restrict__ fc1,
                                                   const float* __restrict__ x,
                                                   unsigned* __restrict__ wpk,
                                                   int* __restrict__ bcnt,
                                                   float* __restrict__ sums,
                                                   unsigned short* __restrict__ xb, int n64) {
    int gid = blockIdx.x * 256 + threadIdx.x;
    if (gid < 512) bcnt[gid] = 0;
    if (gid < 8192) sums[gid] = 0.f;
    if (gid < 2048)       packone(w0_0, wpk + 0,     gid - 0,     32, 64);
    else if (gid < 4096)  packone(w0_1, wpk + 2048,  gid - 2048,  32, 64);
    else if (gid < 8192)  packone(w1_0, wpk + 4096,  gid - 4096,  32, 128);
    else if (gid < 12288) packone(w1_1, wpk + 8192,  gid - 8192,  32, 128);
    else if (gid < 16384) packone(r_0,  wpk + 12288, gid - 12288, 32, 128);
    else if (gid < 20480) packone(r_1,  wpk + 16384, gid - 16384, 32, 128);
    else if (gid < 36864) packone(fc1,  wpk + 20480, gid - 20480, 128, 128);
    if (gid < n64) xb[gid] = bf16of(x[gid]);
}

// --- CSR build --------------------------------------------------------------

// bin edges into fixed-stride bucket segments; bcnt[b] accumulates counts.
__global__ __launch_bounds__(512) void kC_bin(const int* __restrict__ ei0,
                                              const int* __restrict__ ei1,
                                              int* __restrict__ bcnt,
                                              unsigned* __restrict__ binned,
                                              int E, int n) {
    __shared__ int cnt[512];
    __shared__ int base[512];
    int t = threadIdx.x;
    cnt[t] = 0;
    int E2 = 2 * E;
    int e0 = blockIdx.x * 8192;
    unsigned pk[16];
    int bk[16];
    __syncthreads();
#pragma unroll
    for (int j = 0; j < 16; ++j) {
        int ge = e0 + t + j * 512;
        bk[j] = -1;
        if (ge < E2) {
            int slice = ge >= E;
            const int* ei = slice ? ei1 : ei0;
            int e = ge - slice * E;
            int col = ei[E + e], row = ei[e];
            int gcol = slice * n + col;
            bk[j] = gcol >> 8;
            pk[j] = (unsigned)row | (((unsigned)gcol & 255u) << 16);
            atomicAdd(&cnt[bk[j]], 1);
        }
    }
    __syncthreads();
    {
        int c = cnt[t];
        base[t] = c ? atomicAdd(&bcnt[t], c) : 0;
    }
    __syncthreads();
    cnt[t] = 0;
    __syncthreads();
#pragma unroll
    for (int j = 0; j < 16; ++j) {
        if (bk[j] >= 0) {
            int loc = atomicAdd(&cnt[bk[j]], 1);
            int off = base[bk[j]] + loc;
            if (off < BSTRIDE) binned[(size_t)bk[j] * BSTRIDE + off] = pk[j];
        }
    }
}

// exclusive scan of bcnt[NB] -> bstart[0..NB]
__global__ __launch_bounds__(256) void kB_scan(const int* __restrict__ bcnt,
                                               int* __restrict__ bstart, int NB) {
    __shared__ int tmp[256];
    int t = threadIdx.x, carry = 0;
    for (int bse = 0; bse < NB; bse += 256) {
        int i = bse + t;
        int v = (i < NB) ? bcnt[i] : 0;
        tmp[t] = v;
        __syncthreads();
        for (int off = 1; off < 256; off <<= 1) {
            int u = (t >= off) ? tmp[t - off] : 0;
            __syncthreads();
            tmp[t] += u;
            __syncthreads();
        }
        if (i < NB) bstart[i] = tmp[t] - v + carry;
        carry += tmp[255];
        __syncthreads();
    }
    if (t == 0) bstart[NB] = carry;
}

// one block (512 thr) per 256-col bucket -> rowptr, dinv, csr(u16)
__global__ __launch_bounds__(512) void kD_build(const unsigned* __restrict__ binned,
                                                const int* __restrict__ bstart,
                                                int* __restrict__ rowptr,
                                                float* __restrict__ dinv,
                                                unsigned short* __restrict__ csr,
                                                int n2, int NB) {
    __shared__ int cnt[256];
    __shared__ int scn[256];
    __shared__ int cur[256];
    int b = blockIdx.x, t = threadIdx.x;
    int s = bstart[b], e = bstart[b + 1];
    int m = e - s;
    const unsigned* seg = binned + (size_t)b * BSTRIDE;
    if (t < 256) cnt[t] = 0;
    __syncthreads();
    for (int i = t; i < m; i += 512) atomicAdd(&cnt[(seg[i] >> 16) & 255], 1);
    __syncthreads();
    int v = (t < 256) ? cnt[t] : 0;
    if (t < 256) scn[t] = v;
    __syncthreads();
    for (int off = 1; off < 256; off <<= 1) {
        int u = (t < 256 && t >= off) ? scn[t - off] : 0;
        __syncthreads();
        if (t < 256) scn[t] += u;
        __syncthreads();
    }
    if (t < 256) {
        int excl = scn[t] - v;
        int gcol = b * 256 + t;
        if (gcol < n2) {
            rowptr[gcol] = s + excl;
            dinv[gcol] = v > 0 ? rsqrtf((float)v) : 0.f;
        }
        cur[t] = excl;
    }
    __syncthreads();
    for (int i = t; i < m; i += 512) {
        unsigned p = seg[i];
        int cl = (p >> 16) & 255;
        int pos = s + atomicAdd(&cur[cl], 1);
        csr[pos] = (unsigned short)(p & 0xFFFFu);
    }
    if (b == 0 && t == 0) rowptr[n2] = bstart[NB];
}

// --- fused gather + MFMA GEMM ------------------------------------------------
// Block = 64-node tile. Phase 1: wave w gathers nodes [16w,16w+16) (8 lanes/
// node, 2 passes), weight dinv[src]*dinv[dst], fp32 accum, pack bf16 into LDS
// A-tile (stride 36 u32). Phase 2: de-staged MFMA vs packed W^T; bf16 out +
// fused BN stats (quad shfl-reduce -> LDS -> 8-way replicated global sums).
template <int F>
__global__ __launch_bounds__(256) void gg_kernel(const int* __restrict__ rowptr,
                                                 const unsigned short* __restrict__ csr,
                                                 const unsigned short* __restrict__ mtab,
                                                 size_t slice_stride,
                                                 const float* __restrict__ dinv,
                                                 const unsigned* __restrict__ WT0,
                                                 const unsigned* __restrict__ WT1,
                                                 unsigned short* __restrict__ Cb,
                                                 float* __restrict__ sums_base,
                                                 int roff, int n) {
    constexpr int NC = F / 16;
    __shared__ unsigned As32[64 * 36];
    __shared__ float ls[2 * F];
    int BPS = (n + 63) >> 6;
    int slice = blockIdx.x >= BPS;
    int sb = blockIdx.x - slice * BPS;
    int row0 = slice * n + sb * 64;
    int rows = min(64, n - sb * 64);
    for (int i = threadIdx.x; i < 2 * F; i += 256) ls[i] = 0.f;
    int w = threadIdx.x >> 6, lane = threadIdx.x & 63;
    int l = lane & 7;
    const unsigned short* mb = mtab + slice_stride * slice;
    const float* dsrc = dinv + slice * n;
#pragma unroll
    for (int p = 0; p < 2; ++p) {
        int nl = 16 * w + p * 8 + (lane >> 3);
        float a0 = 0.f, a1 = 0.f, a2 = 0.f, a3 = 0.f, a4 = 0.f, a5 = 0.f, a6 = 0.f, a7 = 0.f;
        if (nl < rows) {
            int node = row0 + nl;
            int s = rowptr[node], e = rowptr[node + 1];
            int b = s;
            for (; b + 8 <= e; b += 8) {
                int idx = csr[b + l];
                float wsrc = dsrc[idx];
                uint4 u[8];
                float ws[8];
#pragma unroll
                for (int j = 0; j < 8; ++j) {
                    int r = __shfl(idx, j, 8);
                    ws[j] = __shfl(wsrc, j, 8);
                    u[j] = *(const uint4*)&mb[(size_t)r * 64 + l * 8];
                }
#pragma unroll
                for (int j = 0; j < 8; ++j) {
                    a0 = fmaf(ws[j], uflo(u[j].x), a0);
                    a1 = fmaf(ws[j], ufhi(u[j].x), a1);
                    a2 = fmaf(ws[j], uflo(u[j].y), a2);
                    a3 = fmaf(ws[j], ufhi(u[j].y), a3);
                    a4 = fmaf(ws[j], uflo(u[j].z), a4);
                    a5 = fmaf(ws[j], ufhi(u[j].z), a5);
                    a6 = fmaf(ws[j], uflo(u[j].w), a6);
                    a7 = fmaf(ws[j], ufhi(u[j].w), a7);
                }
            }
            if (b < e) {
                int cntn = e - b;
                int idx = (b + l < e) ? (int)csr[b + l] : 0;
                float wsrc = dsrc[idx];
                for (int j = 0; j < cntn; ++j) {
                    int r = __shfl(idx, j, 8);
                    float wj = __shfl(wsrc, j, 8);
                    uint4 u = *(const uint4*)&mb[(size_t)r * 64 + l * 8];
                    a0 = fmaf(wj, uflo(u.x), a0);
                    a1 = fmaf(wj, ufhi(u.x), a1);
                    a2 = fmaf(wj, uflo(u.y), a2);
                    a3 = fmaf(wj, ufhi(u.y), a3);
                    a4 = fmaf(wj, uflo(u.z), a4);
                    a5 = fmaf(wj, ufhi(u.z), a5);
                    a6 = fmaf(wj, uflo(u.w), a6);
                    a7 = fmaf(wj, ufhi(u.w), a7);
                }
            }
            float d = dinv[node];
            a0 *= d; a1 *= d; a2 *= d; a3 *= d;
            a4 *= d; a5 *= d; a6 *= d; a7 *= d;
        }
        uint4 o;
        o.x = pack2(a0, a1);
        o.y = pack2(a2, a3);
        o.z = pack2(a4, a5);
        o.w = pack2(a6, a7);
        *(uint4*)&As32[nl * 36 + l * 4] = o;
    }
    __syncthreads();
    const unsigned* WT = slice ? WT1 : WT0;
    int q = lane >> 4, ln = lane & 15;
    v8s af0 = *(const v8s*)&As32[(16 * w + ln) * 36 + q * 4];
    v8s af1 = *(const v8s*)&As32[(16 * w + ln) * 36 + 16 + q * 4];
    f32x4 acc[NC];
#pragma unroll
    for (int ct = 0; ct < NC; ++ct) acc[ct] = {0.f, 0.f, 0.f, 0.f};
#pragma unroll
    for (int ct = 0; ct < NC; ++ct) {
        v8s b0 = *(const v8s*)&WT[(ct * 16 + ln) * 32 + q * 4];
        v8s b1 = *(const v8s*)&WT[(ct * 16 + ln) * 32 + 16 + q * 4];
        acc[ct] = __builtin_amdgcn_mfma_f32_16x16x32_bf16(af0, b0, acc[ct], 0, 0, 0);
        acc[ct] = __builtin_amdgcn_mfma_f32_16x16x32_bf16(af1, b1, acc[ct], 0, 0, 0);
    }
#pragma unroll
    for (int ct = 0; ct < NC; ++ct) {
        float s1 = 0.f, s2 = 0.f;
#pragma unroll
        for (int i = 0; i < 4; ++i) {
            int r = 16 * w + q * 4 + i;
            if (r < rows) {
                float v = acc[ct][i];
                Cb[(size_t)(row0 + r) * F + ct * 16 + ln] = bf16of(v);
                s1 += v;
                s2 += v * v;
            }
        }
        s1 += __shfl_xor(s1, 16); s1 += __shfl_xor(s1, 32);
        s2 += __shfl_xor(s2, 16); s2 += __shfl_xor(s2, 32);
        if (q == 0) {
            atomicAdd(&ls[ct * 16 + ln], s1);
            atomicAdd(&ls[F + ct * 16 + ln], s2);
        }
    }
    __syncthreads();
    if (threadIdx.x < F) {
        float* dst = sums_base + (blockIdx.x & 7) * 1024 + roff + slice * 2 * F;
        unsafeAtomicAdd(&dst[threadIdx.x], ls[threadIdx.x]);
        unsafeAtomicAdd(&dst[F + threadIdx.x], ls[F + threadIdx.x]);
    }
}

// --- pointwise / epilogue kernels (BN-final computed inline from sums) -------

// h1b = bf16(san(relu(bn(t0b)) + x))
__global__ __launch_bounds__(256) void apply0_kernel(const unsigned short* __restrict__ t0b,
                                                     const float* __restrict__ x,
                                                     const float* __restrict__ sums_base,
                                                     int roff,
                                                     const float* __restrict__ g,
                                                     const float* __restrict__ be,
                                                     unsigned short* __restrict__ h1b,
                                                     int n64, int n) {
    __shared__ float sc[128];
    int i0 = blockIdx.x * 256;
    int slice = i0 >= n64;
    int t = threadIdx.x;
    if (t < 64) {
        float s1 = 0.f, s2 = 0.f;
#pragma unroll
        for (int r = 0; r < 8; ++r) {
            const float* src = sums_base + r * 1024 + roff + slice * 128;
            s1 += src[t];
            s2 += src[64 + t];
        }
        float inv_n = 1.0f / (float)n;
        float mu = s1 * inv_n;
        float var = fmaxf(s2 * inv_n - mu * mu, 0.f);
        float scale = g[t] * rsqrtf(var + 1e-5f);
        sc[t] = scale;
        sc[64 + t] = be[t] - mu * scale;
    }
    __syncthreads();
    int i = i0 + t;
    int f = i & 63;
    float v = fmaf(fofbf16(t0b[i]), sc[f], sc[64 + f]);
    v = fmaxf(v, 0.f) + x[i - slice * n64];
    h1b[i] = bf16of(sanf(v));
}

// comb[lrow, slice*128 + c] (bf16) = san(bn(Tb) + h1b @ res_slice)
__global__ __launch_bounds__(256) void mfma_apply1(const unsigned short* __restrict__ h1b,
                                                   const unsigned short* __restrict__ Tb,
                                                   const unsigned* __restrict__ RT0,
                                                   const unsigned* __restrict__ RT1,
                                                   const float* __restrict__ sums_base,
                                                   const float* __restrict__ g,
                                                   const float* __restrict__ be,
                                                   unsigned short* __restrict__ comb, int n) {
    __shared__ float sc[256];
    int BPS = (n + 63) >> 6;
    int slice = blockIdx.x >= BPS;
    int sb = blockIdx.x - slice * BPS;
    int row0 = slice * n + sb * 64;
    int rows = min(64, n - sb * 64);
    int t = threadIdx.x;
    if (t < 128) {
        float s1 = 0.f, s2 = 0.f;
#pragma unroll
        for (int r = 0; r < 8; ++r) {
            const float* src = sums_base + r * 1024 + slice * 256;
            s1 += src[t];
            s2 += src[128 + t];
        }
        float inv_n = 1.0f / (float)n;
        float mu = s1 * inv_n;
        float var = fmaxf(s2 * inv_n - mu * mu, 0.f);
        float scale = g[t] * rsqrtf(var + 1e-5f);
        sc[t] = scale;
        sc[128 + t] = be[t] - mu * scale;
    }
    __syncthreads();
    const unsigned* WT = slice ? RT1 : RT0;
    int w = t >> 6, lane = t & 63, q = lane >> 4, ln = lane & 15;
    const unsigned* A32 = (const unsigned*)h1b;
    size_t arow = (size_t)(row0 + 16 * w + ln) * 32;
    v8s af0 = *(const v8s*)&A32[arow + q * 4];
    v8s af1 = *(const v8s*)&A32[arow + 16 + q * 4];
    f32x4 acc[8];
#pragma unroll
    for (int ct = 0; ct < 8; ++ct) acc[ct] = {0.f, 0.f, 0.f, 0.f};
#pragma unroll
    for (int ct = 0; ct < 8; ++ct) {
        v8s b0 = *(const v8s*)&WT[(ct * 16 + ln) * 32 + q * 4];
        v8s b1 = *(const v8s*)&WT[(ct * 16 + ln) * 32 + 16 + q * 4];
        acc[ct] = __builtin_amdgcn_mfma_f32_16x16x32_bf16(af0, b0, acc[ct], 0, 0, 0);
        acc[ct] = __builtin_amdgcn_mfma_f32_16x16x32_bf16(af1, b1, acc[ct], 0, 0, 0);
    }
#pragma unroll
    for (int ct = 0; ct < 8; ++ct) {
        int c = ct * 16 + ln;
        float scale = sc[c], shift = sc[128 + c];
#pragma unroll
        for (int i = 0; i < 4; ++i) {
            int r = 16 * w + q * 4 + i;
            if (r >= rows) continue;
            int row = row0 + r;
            float tv = fofbf16(Tb[(size_t)row * 128 + c]);
            float o = sanf(fmaf(tv, scale, shift) + acc[ct][i]);
            comb[(size_t)(row - slice * n) * 256 + slice * 128 + c] = bf16of(o);
        }
    }
}

// fused head: h = relu(comb @ fc1 + b1); logits = h @ fc2 + b2; softmax.
__global__ __launch_bounds__(256) void mfma_head_fc2(const unsigned short* __restrict__ comb,
                                                     const unsigned* __restrict__ FT,
                                                     const float* __restrict__ bias,
                                                     const float* __restrict__ w2,
                                                     const float* __restrict__ b2,
                                                     float* __restrict__ out, int n) {
    int row0 = blockIdx.x * 64;
    int rows = min(64, n - row0);
    int w = threadIdx.x >> 6, lane = threadIdx.x & 63, q = lane >> 4, ln = lane & 15;
    const unsigned* A32 = (const unsigned*)comb;
    size_t arow = (size_t)(row0 + 16 * w + ln) * 128;
    f32x4 acc[8];
#pragma unroll
    for (int ct = 0; ct < 8; ++ct) acc[ct] = {0.f, 0.f, 0.f, 0.f};
#pragma unroll
    for (int kt = 0; kt < 4; ++kt) {
        v8s af0 = *(const v8s*)&A32[arow + kt * 32 + q * 4];
        v8s af1 = *(const v8s*)&A32[arow + kt * 32 + 16 + q * 4];
#pragma unroll
        for (int ct = 0; ct < 8; ++ct) {
            v8s b0 = *(const v8s*)&FT[(ct * 16 + ln) * 128 + kt * 32 + q * 4];
            v8s b1 = *(const v8s*)&FT[(ct * 16 + ln) * 128 + kt * 32 + 16 + q * 4];
            acc[ct] = __builtin_amdgcn_mfma_f32_16x16x32_bf16(af0, b0, acc[ct], 0, 0, 0);
            acc[ct] = __builtin_amdgcn_mfma_f32_16x16x32_bf16(af1, b1, acc[ct], 0, 0, 0);
        }
    }
    float p0[4] = {0.f, 0.f, 0.f, 0.f}, p1[4] = {0.f, 0.f, 0.f, 0.f};
#pragma unroll
    for (int ct = 0; ct < 8; ++ct) {
        int c = ct * 16 + ln;
        float bi = bias[c];
        float w20 = w2[c * 2], w21 = w2[c * 2 + 1];
#pragma unroll
        for (int i = 0; i < 4; ++i) {
            float h = fmaxf(acc[ct][i] + bi, 0.f);
            p0[i] = fmaf(h, w20, p0[i]);
            p1[i] = fmaf(h, w21, p1[i]);
        }
    }
#pragma unroll
    for (int i = 0; i < 4; ++i) {
#pragma unroll
        for (int msk = 1; msk < 16; msk <<= 1) {
            p0[i] += __shfl_xor(p0[i], msk);
            p1[i] += __shfl_xor(p1[i], msk);
        }
    }
    if (ln == 0) {
        float bb0 = b2[0], bb1 = b2[1];
#pragma unroll
        for (int i = 0; i < 4; ++i) {
            int r = 16 * w + q * 4 + i;
            if (r >= rows) continue;
            int R = row0 + r;
            float l0 = p0[i] + bb0, l1 = p1[i] + bb1;
            float mx = fmaxf(l0, l1);
            float e0 = expf(l0 - mx), e1 = expf(l1 - mx);
            float inv = 1.0f / (e0 + e1);
            out[(size_t)R * 2] = l0;
            out[(size_t)R * 2 + 1] = l1;
            out[(size_t)2 * n + R * 2] = e0 * inv;
            out[(size_t)2 * n + R * 2 + 1] = e1 * inv;
        }
    }
}

static inline int cdiv(int a, int b) { return (a + b - 1) / b; }

extern "C" void kernel_launch(void* const* d_in, const int* in_sizes, int n_in,
                              void* d_out, int out_size, void* d_ws, size_t ws_size,
                              hipStream_t stream) {
    const float* x       = (const float*)d_in[0];
    const int*   ei0     = (const int*)d_in[1];
    const int*   ei1     = (const int*)d_in[2];
    const float* w0_s0   = (const float*)d_in[3];
    const float* w1_s0   = (const float*)d_in[5];
    const float* res1_s0 = (const float*)d_in[7];
    const float* w0_s1   = (const float*)d_in[8];
    const float* w1_s1   = (const float*)d_in[10];
    const float* res1_s1 = (const float*)d_in[12];
    const float* bn_g0   = (const float*)d_in[13];
    const float* bn_b0   = (const float*)d_in[14];
    const float* bn_g1   = (const float*)d_in[15];
    const float* bn_b1   = (const float*)d_in[16];
    const float* fc1_w   = (const float*)d_in[17];
    const float* fc1_b   = (const float*)d_in[18];
    const float* fc2_w   = (const float*)d_in[19];
    const float* fc2_b   = (const float*)d_in[20];
    float* out = (float*)d_out;

    int n = in_sizes[0] / 64;   // 50000
    int E = in_sizes[1] / 2;    // 1600000
    int n2 = 2 * n, E2 = 2 * E;
    int n64 = n * 64;
    int NB = cdiv(n2, 256);     // 391 buckets (256 cols each)
    int BPS = cdiv(n, 64);      // 782 row-tiles per slice

    // workspace layout (binned overlays comb; t0b overlays Tb):
    unsigned short* Tb   = (unsigned short*)d_ws;        // [2n*128] (t0b = first 2n*64)
    unsigned short* h1b  = Tb + (size_t)n2 * 128;        // [2n*64]
    unsigned short* comb = h1b + (size_t)n2 * 64;        // [n*256]
    unsigned short* xb   = comb + (size_t)n * 256;       // [n*64] shared unscaled table
    float* dinv = (float*)(xb + (size_t)n * 64);         // [2n]
    float* sums = dinv + n2;                             // [8][1024] replicas
    unsigned* wpk = (unsigned*)(sums + 8192);            // [36864]
    unsigned short* csr = (unsigned short*)(wpk + 36864);// [E2] u16
    int* rowptr = (int*)(csr + (size_t)E2);              // [2n+1]
    int* bcnt   = rowptr + (n2 + 1);                     // [512]
    int* bstart = bcnt + 512;                            // [NB+1]
    unsigned short* t0b = Tb;
    unsigned* binned = (unsigned*)comb;                  // [NB*BSTRIDE] = 16MB <= 25.6MB
    unsigned* w0T0 = wpk + 0,    *w0T1 = wpk + 2048;
    unsigned* w1T0 = wpk + 4096, *w1T1 = wpk + 8192;
    unsigned* rT0  = wpk + 12288,*rT1  = wpk + 16384;
    unsigned* fT   = wpk + 20480;

    // --- prep (weights + zeroing + xb) + CSR build ---
    prep_kernel<<<cdiv(n64, 256), 256, 0, stream>>>(w0_s0, w0_s1, w1_s0, w1_s1,
                                                    res1_s0, res1_s1, fc1_w, x,
                                                    wpk, bcnt, sums, xb, n64);
    kC_bin<<<cdiv(E2, 8192), 512, 0, stream>>>(ei0, ei1, bcnt, binned, E, n);
    kB_scan<<<1, 256, 0, stream>>>(bcnt, bstart, NB);
    kD_build<<<NB, 512, 0, stream>>>(binned, bstart, rowptr, dinv, csr, n2, NB);

    // --- layer 0: fused gather(xb)+@W0+stats -> apply0 (bn inline) ---
    gg_kernel<64><<<2 * BPS, 256, 0, stream>>>(rowptr, csr, xb, 0, dinv,
                                               w0T0, w0T1, t0b, sums, 512, n);
    apply0_kernel<<<2 * n64 / 256, 256, 0, stream>>>(t0b, x, sums, 512, bn_g0, bn_b0,
                                                     h1b, n64, n);

    // --- layer 1: fused gather(h1b)+@W1+stats -> apply1 (bn inline + res GEMM) ---
    gg_kernel<128><<<2 * BPS, 256, 0, stream>>>(rowptr, csr, h1b, (size_t)n * 64, dinv,
                                                w1T0, w1T1, Tb, sums, 0, n);
    mfma_apply1<<<2 * BPS, 256, 0, stream>>>(h1b, Tb, rT0, rT1, sums, bn_g1, bn_b1,
                                             comb, n);

    // --- fused head + fc2 + softmax ---
    mfma_head_fc2<<<BPS, 256, 0, stream>>>(comb, fT, fc1_b, fc2_w, fc2_b, out, n);
}

// Round 14
// 399.443 us; speedup vs baseline: 1.0221x; 1.0221x over previous
//
#include <hip/hip_runtime.h>
#include <hip/hip_bf16.h>
#include <math.h>

// ---------------------------------------------------------------------------
// DriverGeneGNN: 2-slice GCN (64->64->128) + BN + residual + MLP head.
// N=50000, E=1600000. fp32 accumulate, bf16 operands + bf16 intermediates.
// R14: revert R13's gather+GEMM fusion (block-wide barrier serialized on
//      slowest-degree node; occ 51->24%). Keep the good parts: weighted
//      gather (per-edge dinv[src], dinv[dst] at writeback) reading a SHARED
//      6.4MB unscaled xb table (layer 0) / h1b directly (layer 1, no h1sb);
//      BN-final inline in apply prologues; no prescale. 11 dispatches.
// CSR build (R12): kC bins into fixed-stride bucket segments, kB scan, kD.
// GEMMs (R12): de-staged MFMA vs L2-resident packed W^T, fused BN stats.
// MFMA frag layouts (HW-verified): A[m=lane&15][k=(lane>>4)*8+j],
//     B[k][n=lane&15], C/D col=lane&15 row=(lane>>4)*4+reg.
// Conv biases cancel in BN -> skipped.
// ---------------------------------------------------------------------------

typedef short v8s __attribute__((ext_vector_type(8)));
typedef float f32x4 __attribute__((ext_vector_type(4)));

#define BSTRIDE 10240  // u32 slots per 256-col bucket segment (mean 8184)

__device__ __forceinline__ float sanf(float v) {
    if (v != v) return 0.f;
    if (isinf(v)) return v > 0.f ? 100.f : -100.f;
    return v;
}

__device__ __forceinline__ unsigned short bf16of(float v) {
    __hip_bfloat16 h = __float2bfloat16(v);
    return *(unsigned short*)&h;
}
__device__ __forceinline__ unsigned pack2(float lo, float hi) {
    return (unsigned)bf16of(lo) | ((unsigned)bf16of(hi) << 16);
}
__device__ __forceinline__ float uflo(unsigned u) { return __uint_as_float(u << 16); }
__device__ __forceinline__ float ufhi(unsigned u) { return __uint_as_float(u & 0xFFFF0000u); }
__device__ __forceinline__ float fofbf16(unsigned short u) {
    return __uint_as_float(((unsigned)u) << 16);
}

// --- prep: pack weights (W^T bf16-pairs), zero bcnt/sums, xb = bf16(x) ------
__device__ __forceinline__ void packone(const float* __restrict__ src, unsigned* __restrict__ dst,
                                        int L, int Khalf, int F) {
    int c = L / Khalf, kp = L - c * Khalf;
    dst[L] = pack2(src[(2 * kp) * F + c], src[(2 * kp + 1) * F + c]);
}

__global__ __launch_bounds__(256) void prep_kernel(const float* __restrict__ w0_0,
                                                   const float* __restrict__ w0_1,
                                                   const float* __restrict__ w1_0,
                                                   const float* __restrict__ w1_1,
                                                   const float* __restrict__ r_0,
                                                   const float* __restrict__ r_1,
                                                   const float* __restrict__ fc1,
                                                   const float* __restrict__ x,
                                                   unsigned* __restrict__ wpk,
                                                   int* __restrict__ bcnt,
                                                   float* __restrict__ sums,
                                                   unsigned short* __restrict__ xb, int n64) {
    int gid = blockIdx.x * 256 + threadIdx.x;
    if (gid < 512) bcnt[gid] = 0;
    if (gid < 8192) sums[gid] = 0.f;
    if (gid < 2048)       packone(w0_0, wpk + 0,     gid - 0,     32, 64);
    else if (gid < 4096)  packone(w0_1, wpk + 2048,  gid - 2048,  32, 64);
    else if (gid < 8192)  packone(w1_0, wpk + 4096,  gid - 4096,  32, 128);
    else if (gid < 12288) packone(w1_1, wpk + 8192,  gid - 8192,  32, 128);
    else if (gid < 16384) packone(r_0,  wpk + 12288, gid - 12288, 32, 128);
    else if (gid < 20480) packone(r_1,  wpk + 16384, gid - 16384, 32, 128);
    else if (gid < 36864) packone(fc1,  wpk + 20480, gid - 20480, 128, 128);
    if (gid < n64) xb[gid] = bf16of(x[gid]);
}

// --- CSR build (R12) ---------------------------------------------------------

__global__ __launch_bounds__(512) void kC_bin(const int* __restrict__ ei0,
                                              const int* __restrict__ ei1,
                                              int* __restrict__ bcnt,
                                              unsigned* __restrict__ binned,
                                              int E, int n) {
    __shared__ int cnt[512];
    __shared__ int base[512];
    int t = threadIdx.x;
    cnt[t] = 0;
    int E2 = 2 * E;
    int e0 = blockIdx.x * 8192;
    unsigned pk[16];
    int bk[16];
    __syncthreads();
#pragma unroll
    for (int j = 0; j < 16; ++j) {
        int ge = e0 + t + j * 512;
        bk[j] = -1;
        if (ge < E2) {
            int slice = ge >= E;
            const int* ei = slice ? ei1 : ei0;
            int e = ge - slice * E;
            int col = ei[E + e], row = ei[e];
            int gcol = slice * n + col;
            bk[j] = gcol >> 8;
            pk[j] = (unsigned)row | (((unsigned)gcol & 255u) << 16);
            atomicAdd(&cnt[bk[j]], 1);
        }
    }
    __syncthreads();
    {
        int c = cnt[t];
        base[t] = c ? atomicAdd(&bcnt[t], c) : 0;
    }
    __syncthreads();
    cnt[t] = 0;
    __syncthreads();
#pragma unroll
    for (int j = 0; j < 16; ++j) {
        if (bk[j] >= 0) {
            int loc = atomicAdd(&cnt[bk[j]], 1);
            int off = base[bk[j]] + loc;
            if (off < BSTRIDE) binned[(size_t)bk[j] * BSTRIDE + off] = pk[j];
        }
    }
}

__global__ __launch_bounds__(256) void kB_scan(const int* __restrict__ bcnt,
                                               int* __restrict__ bstart, int NB) {
    __shared__ int tmp[256];
    int t = threadIdx.x, carry = 0;
    for (int bse = 0; bse < NB; bse += 256) {
        int i = bse + t;
        int v = (i < NB) ? bcnt[i] : 0;
        tmp[t] = v;
        __syncthreads();
        for (int off = 1; off < 256; off <<= 1) {
            int u = (t >= off) ? tmp[t - off] : 0;
            __syncthreads();
            tmp[t] += u;
            __syncthreads();
        }
        if (i < NB) bstart[i] = tmp[t] - v + carry;
        carry += tmp[255];
        __syncthreads();
    }
    if (t == 0) bstart[NB] = carry;
}

__global__ __launch_bounds__(512) void kD_build(const unsigned* __restrict__ binned,
                                                const int* __restrict__ bstart,
                                                int* __restrict__ rowptr,
                                                float* __restrict__ dinv,
                                                unsigned short* __restrict__ csr,
                                                int n2, int NB) {
    __shared__ int cnt[256];
    __shared__ int scn[256];
    __shared__ int cur[256];
    int b = blockIdx.x, t = threadIdx.x;
    int s = bstart[b], e = bstart[b + 1];
    int m = e - s;
    const unsigned* seg = binned + (size_t)b * BSTRIDE;
    if (t < 256) cnt[t] = 0;
    __syncthreads();
    for (int i = t; i < m; i += 512) atomicAdd(&cnt[(seg[i] >> 16) & 255], 1);
    __syncthreads();
    int v = (t < 256) ? cnt[t] : 0;
    if (t < 256) scn[t] = v;
    __syncthreads();
    for (int off = 1; off < 256; off <<= 1) {
        int u = (t < 256 && t >= off) ? scn[t - off] : 0;
        __syncthreads();
        if (t < 256) scn[t] += u;
        __syncthreads();
    }
    if (t < 256) {
        int excl = scn[t] - v;
        int gcol = b * 256 + t;
        if (gcol < n2) {
            rowptr[gcol] = s + excl;
            dinv[gcol] = v > 0 ? rsqrtf((float)v) : 0.f;
        }
        cur[t] = excl;
    }
    __syncthreads();
    for (int i = t; i < m; i += 512) {
        unsigned p = seg[i];
        int cl = (p >> 16) & 255;
        int pos = s + atomicAdd(&cur[cl], 1);
        csr[pos] = (unsigned short)(p & 0xFFFFu);
    }
    if (b == 0 && t == 0) rowptr[n2] = bstart[NB];
}

// --- weighted gather (bf16 table, per-edge dinv[src], dinv[dst] at out) -----
// 8 lanes/node, 8 16B loads in flight; out = bf16, scaled.
__global__ __launch_bounds__(256) void gatherw_kernel(const int* __restrict__ rowptr,
                                                      const unsigned short* __restrict__ csr,
                                                      const unsigned short* __restrict__ mtab,
                                                      size_t slice_stride,
                                                      const float* __restrict__ dinv,
                                                      unsigned short* __restrict__ outb,
                                                      int n, int n2) {
    int gid = blockIdx.x * 256 + threadIdx.x;
    int node = gid >> 3;
    if (node >= n2) return;
    int l = threadIdx.x & 7;
    int slice = node >= n;
    const unsigned short* mb = mtab + slice_stride * slice;
    const float* dsrc = dinv + (size_t)slice * n;
    int s = rowptr[node], e = rowptr[node + 1];
    float a0 = 0.f, a1 = 0.f, a2 = 0.f, a3 = 0.f, a4 = 0.f, a5 = 0.f, a6 = 0.f, a7 = 0.f;
    int b = s;
    for (; b + 8 <= e; b += 8) {
        int idx = csr[b + l];
        float wsrc = dsrc[idx];
        uint4 u[8];
        float ws[8];
#pragma unroll
        for (int j = 0; j < 8; ++j) {
            int r = __shfl(idx, j, 8);
            ws[j] = __shfl(wsrc, j, 8);
            u[j] = *(const uint4*)&mb[(size_t)r * 64 + l * 8];
        }
#pragma unroll
        for (int j = 0; j < 8; ++j) {
            a0 = fmaf(ws[j], uflo(u[j].x), a0);
            a1 = fmaf(ws[j], ufhi(u[j].x), a1);
            a2 = fmaf(ws[j], uflo(u[j].y), a2);
            a3 = fmaf(ws[j], ufhi(u[j].y), a3);
            a4 = fmaf(ws[j], uflo(u[j].z), a4);
            a5 = fmaf(ws[j], ufhi(u[j].z), a5);
            a6 = fmaf(ws[j], uflo(u[j].w), a6);
            a7 = fmaf(ws[j], ufhi(u[j].w), a7);
        }
    }
    if (b < e) {
        int cntn = e - b;
        int idx = (b + l < e) ? (int)csr[b + l] : 0;
        float wsrc = dsrc[idx];
        for (int j = 0; j < cntn; ++j) {
            int r = __shfl(idx, j, 8);
            float wj = __shfl(wsrc, j, 8);
            uint4 u = *(const uint4*)&mb[(size_t)r * 64 + l * 8];
            a0 = fmaf(wj, uflo(u.x), a0);
            a1 = fmaf(wj, ufhi(u.x), a1);
            a2 = fmaf(wj, uflo(u.y), a2);
            a3 = fmaf(wj, ufhi(u.y), a3);
            a4 = fmaf(wj, uflo(u.z), a4);
            a5 = fmaf(wj, ufhi(u.z), a5);
            a6 = fmaf(wj, uflo(u.w), a6);
            a7 = fmaf(wj, ufhi(u.w), a7);
        }
    }
    float d = dinv[node];
    uint4 o;
    o.x = pack2(a0 * d, a1 * d);
    o.y = pack2(a2 * d, a3 * d);
    o.z = pack2(a4 * d, a5 * d);
    o.w = pack2(a6 * d, a7 * d);
    *(uint4*)&outb[(size_t)node * 64 + l * 8] = o;
}

// --- de-staged MFMA GEMMs (R12) ---------------------------------------------

// Cb[2n,F] bf16 = Ab[2n,64] @ W_slice; fused BN stats -> replicated sums.
template <int F>
__global__ __launch_bounds__(256) void mfma_gemmb(const unsigned short* __restrict__ Ab,
                                                  const unsigned* __restrict__ WT0,
                                                  const unsigned* __restrict__ WT1,
                                                  unsigned short* __restrict__ Cb,
                                                  float* __restrict__ sums_base,
                                                  int roff, int n) {
    constexpr int NC = F / 16;
    __shared__ float ls[2 * F];
    int BPS = (n + 63) >> 6;
    int slice = blockIdx.x >= BPS;
    int sb = blockIdx.x - slice * BPS;
    const unsigned* WT = slice ? WT1 : WT0;
    int row0 = slice * n + sb * 64;
    int rows = min(64, n - sb * 64);
    for (int i = threadIdx.x; i < 2 * F; i += 256) ls[i] = 0.f;
    int w = threadIdx.x >> 6, lane = threadIdx.x & 63, q = lane >> 4, ln = lane & 15;
    const unsigned* A32 = (const unsigned*)Ab;
    size_t arow = (size_t)(row0 + 16 * w + ln) * 32;
    v8s af0 = *(const v8s*)&A32[arow + q * 4];
    v8s af1 = *(const v8s*)&A32[arow + 16 + q * 4];
    f32x4 acc[NC];
#pragma unroll
    for (int ct = 0; ct < NC; ++ct) acc[ct] = {0.f, 0.f, 0.f, 0.f};
#pragma unroll
    for (int ct = 0; ct < NC; ++ct) {
        v8s b0 = *(const v8s*)&WT[(ct * 16 + ln) * 32 + q * 4];
        v8s b1 = *(const v8s*)&WT[(ct * 16 + ln) * 32 + 16 + q * 4];
        acc[ct] = __builtin_amdgcn_mfma_f32_16x16x32_bf16(af0, b0, acc[ct], 0, 0, 0);
        acc[ct] = __builtin_amdgcn_mfma_f32_16x16x32_bf16(af1, b1, acc[ct], 0, 0, 0);
    }
    __syncthreads();  // ls zero-init visible
#pragma unroll
    for (int ct = 0; ct < NC; ++ct) {
        float s1 = 0.f, s2 = 0.f;
#pragma unroll
        for (int i = 0; i < 4; ++i) {
            int r = 16 * w + q * 4 + i;
            if (r < rows) {
                float v = acc[ct][i];
                Cb[(size_t)(row0 + r) * F + ct * 16 + ln] = bf16of(v);
                s1 += v;
                s2 += v * v;
            }
        }
        s1 += __shfl_xor(s1, 16); s1 += __shfl_xor(s1, 32);
        s2 += __shfl_xor(s2, 16); s2 += __shfl_xor(s2, 32);
        if (q == 0) {
            atomicAdd(&ls[ct * 16 + ln], s1);
            atomicAdd(&ls[F + ct * 16 + ln], s2);
        }
    }
    __syncthreads();
    if (threadIdx.x < F) {
        float* dst = sums_base + (blockIdx.x & 7) * 1024 + roff + slice * 2 * F;
        unsafeAtomicAdd(&dst[threadIdx.x], ls[threadIdx.x]);
        unsafeAtomicAdd(&dst[F + threadIdx.x], ls[F + threadIdx.x]);
    }
}

// --- pointwise / epilogue kernels (BN-final inline from replicated sums) ----

// h1b = bf16(san(relu(bn(t0b)) + x))
__global__ __launch_bounds__(256) void apply0_kernel(const unsigned short* __restrict__ t0b,
                                                     const float* __restrict__ x,
                                                     const float* __restrict__ sums_base,
                                                     int roff,
                                                     const float* __restrict__ g,
                                                     const float* __restrict__ be,
                                                     unsigned short* __restrict__ h1b,
                                                     int n64, int n) {
    __shared__ float sc[128];
    int i0 = blockIdx.x * 256;
    int slice = i0 >= n64;
    int t = threadIdx.x;
    if (t < 64) {
        float s1 = 0.f, s2 = 0.f;
#pragma unroll
        for (int r = 0; r < 8; ++r) {
            const float* src = sums_base + r * 1024 + roff + slice * 128;
            s1 += src[t];
            s2 += src[64 + t];
        }
        float inv_n = 1.0f / (float)n;
        float mu = s1 * inv_n;
        float var = fmaxf(s2 * inv_n - mu * mu, 0.f);
        float scale = g[t] * rsqrtf(var + 1e-5f);
        sc[t] = scale;
        sc[64 + t] = be[t] - mu * scale;
    }
    __syncthreads();
    int i = i0 + t;
    int f = i & 63;
    float v = fmaf(fofbf16(t0b[i]), sc[f], sc[64 + f]);
    v = fmaxf(v, 0.f) + x[i - slice * n64];
    h1b[i] = bf16of(sanf(v));
}

// comb[lrow, slice*128 + c] (bf16) = san(bn(Tb) + h1b @ res_slice)
__global__ __launch_bounds__(256) void mfma_apply1(const unsigned short* __restrict__ h1b,
                                                   const unsigned short* __restrict__ Tb,
                                                   const unsigned* __restrict__ RT0,
                                                   const unsigned* __restrict__ RT1,
                                                   const float* __restrict__ sums_base,
                                                   const float* __restrict__ g,
                                                   const float* __restrict__ be,
                                                   unsigned short* __restrict__ comb, int n) {
    __shared__ float sc[256];
    int BPS = (n + 63) >> 6;
    int slice = blockIdx.x >= BPS;
    int sb = blockIdx.x - slice * BPS;
    int row0 = slice * n + sb * 64;
    int rows = min(64, n - sb * 64);
    int t = threadIdx.x;
    if (t < 128) {
        float s1 = 0.f, s2 = 0.f;
#pragma unroll
        for (int r = 0; r < 8; ++r) {
            const float* src = sums_base + r * 1024 + slice * 256;
            s1 += src[t];
            s2 += src[128 + t];
        }
        float inv_n = 1.0f / (float)n;
        float mu = s1 * inv_n;
        float var = fmaxf(s2 * inv_n - mu * mu, 0.f);
        float scale = g[t] * rsqrtf(var + 1e-5f);
        sc[t] = scale;
        sc[128 + t] = be[t] - mu * scale;
    }
    __syncthreads();
    const unsigned* WT = slice ? RT1 : RT0;
    int w = t >> 6, lane = t & 63, q = lane >> 4, ln = lane & 15;
    const unsigned* A32 = (const unsigned*)h1b;
    size_t arow = (size_t)(row0 + 16 * w + ln) * 32;
    v8s af0 = *(const v8s*)&A32[arow + q * 4];
    v8s af1 = *(const v8s*)&A32[arow + 16 + q * 4];
    f32x4 acc[8];
#pragma unroll
    for (int ct = 0; ct < 8; ++ct) acc[ct] = {0.f, 0.f, 0.f, 0.f};
#pragma unroll
    for (int ct = 0; ct < 8; ++ct) {
        v8s b0 = *(const v8s*)&WT[(ct * 16 + ln) * 32 + q * 4];
        v8s b1 = *(const v8s*)&WT[(ct * 16 + ln) * 32 + 16 + q * 4];
        acc[ct] = __builtin_amdgcn_mfma_f32_16x16x32_bf16(af0, b0, acc[ct], 0, 0, 0);
        acc[ct] = __builtin_amdgcn_mfma_f32_16x16x32_bf16(af1, b1, acc[ct], 0, 0, 0);
    }
#pragma unroll
    for (int ct = 0; ct < 8; ++ct) {
        int c = ct * 16 + ln;
        float scale = sc[c], shift = sc[128 + c];
#pragma unroll
        for (int i = 0; i < 4; ++i) {
            int r = 16 * w + q * 4 + i;
            if (r >= rows) continue;
            int row = row0 + r;
            float tv = fofbf16(Tb[(size_t)row * 128 + c]);
            float o = sanf(fmaf(tv, scale, shift) + acc[ct][i]);
            comb[(size_t)(row - slice * n) * 256 + slice * 128 + c] = bf16of(o);
        }
    }
}

// fused head: h = relu(comb @ fc1 + b1); logits = h @ fc2 + b2; softmax.
__global__ __launch_bounds__(256) void mfma_head_fc2(const unsigned short* __restrict__ comb,
                                                     const unsigned* __restrict__ FT,
                                                     const float* __restrict__ bias,
                                                     const float* __restrict__ w2,
                                                     const float* __restrict__ b2,
                                                     float* __restrict__ out, int n) {
    int row0 = blockIdx.x * 64;
    int rows = min(64, n - row0);
    int w = threadIdx.x >> 6, lane = threadIdx.x & 63, q = lane >> 4, ln = lane & 15;
    const unsigned* A32 = (const unsigned*)comb;
    size_t arow = (size_t)(row0 + 16 * w + ln) * 128;
    f32x4 acc[8];
#pragma unroll
    for (int ct = 0; ct < 8; ++ct) acc[ct] = {0.f, 0.f, 0.f, 0.f};
#pragma unroll
    for (int kt = 0; kt < 4; ++kt) {
        v8s af0 = *(const v8s*)&A32[arow + kt * 32 + q * 4];
        v8s af1 = *(const v8s*)&A32[arow + kt * 32 + 16 + q * 4];
#pragma unroll
        for (int ct = 0; ct < 8; ++ct) {
            v8s b0 = *(const v8s*)&FT[(ct * 16 + ln) * 128 + kt * 32 + q * 4];
            v8s b1 = *(const v8s*)&FT[(ct * 16 + ln) * 128 + kt * 32 + 16 + q * 4];
            acc[ct] = __builtin_amdgcn_mfma_f32_16x16x32_bf16(af0, b0, acc[ct], 0, 0, 0);
            acc[ct] = __builtin_amdgcn_mfma_f32_16x16x32_bf16(af1, b1, acc[ct], 0, 0, 0);
        }
    }
    float p0[4] = {0.f, 0.f, 0.f, 0.f}, p1[4] = {0.f, 0.f, 0.f, 0.f};
#pragma unroll
    for (int ct = 0; ct < 8; ++ct) {
        int c = ct * 16 + ln;
        float bi = bias[c];
        float w20 = w2[c * 2], w21 = w2[c * 2 + 1];
#pragma unroll
        for (int i = 0; i < 4; ++i) {
            float h = fmaxf(acc[ct][i] + bi, 0.f);
            p0[i] = fmaf(h, w20, p0[i]);
            p1[i] = fmaf(h, w21, p1[i]);
        }
    }
#pragma unroll
    for (int i = 0; i < 4; ++i) {
#pragma unroll
        for (int msk = 1; msk < 16; msk <<= 1) {
            p0[i] += __shfl_xor(p0[i], msk);
            p1[i] += __shfl_xor(p1[i], msk);
        }
    }
    if (ln == 0) {
        float bb0 = b2[0], bb1 = b2[1];
#pragma unroll
        for (int i = 0; i < 4; ++i) {
            int r = 16 * w + q * 4 + i;
            if (r >= rows) continue;
            int R = row0 + r;
            float l0 = p0[i] + bb0, l1 = p1[i] + bb1;
            float mx = fmaxf(l0, l1);
            float e0 = expf(l0 - mx), e1 = expf(l1 - mx);
            float inv = 1.0f / (e0 + e1);
            out[(size_t)R * 2] = l0;
            out[(size_t)R * 2 + 1] = l1;
            out[(size_t)2 * n + R * 2] = e0 * inv;
            out[(size_t)2 * n + R * 2 + 1] = e1 * inv;
        }
    }
}

static inline int cdiv(int a, int b) { return (a + b - 1) / b; }

extern "C" void kernel_launch(void* const* d_in, const int* in_sizes, int n_in,
                              void* d_out, int out_size, void* d_ws, size_t ws_size,
                              hipStream_t stream) {
    const float* x       = (const float*)d_in[0];
    const int*   ei0     = (const int*)d_in[1];
    const int*   ei1     = (const int*)d_in[2];
    const float* w0_s0   = (const float*)d_in[3];
    const float* w1_s0   = (const float*)d_in[5];
    const float* res1_s0 = (const float*)d_in[7];
    const float* w0_s1   = (const float*)d_in[8];
    const float* w1_s1   = (const float*)d_in[10];
    const float* res1_s1 = (const float*)d_in[12];
    const float* bn_g0   = (const float*)d_in[13];
    const float* bn_b0   = (const float*)d_in[14];
    const float* bn_g1   = (const float*)d_in[15];
    const float* bn_b1   = (const float*)d_in[16];
    const float* fc1_w   = (const float*)d_in[17];
    const float* fc1_b   = (const float*)d_in[18];
    const float* fc2_w   = (const float*)d_in[19];
    const float* fc2_b   = (const float*)d_in[20];
    float* out = (float*)d_out;

    int n = in_sizes[0] / 64;   // 50000
    int E = in_sizes[1] / 2;    // 1600000
    int n2 = 2 * n, E2 = 2 * E;
    int n64 = n * 64;
    int NB = cdiv(n2, 256);     // 391 buckets (256 cols each)
    int BPS = cdiv(n, 64);      // 782 row-tiles per slice

    // workspace layout (binned overlays comb; t0b overlays Tb):
    unsigned short* Tb   = (unsigned short*)d_ws;        // [2n*128] (t0b = first 2n*64)
    unsigned short* h1b  = Tb + (size_t)n2 * 128;        // [2n*64]
    unsigned short* comb = h1b + (size_t)n2 * 64;        // [n*256]
    unsigned short* Gb   = comb + (size_t)n * 256;       // [2n*64] gather out
    unsigned short* xb   = Gb + (size_t)n2 * 64;         // [n*64] shared unscaled table
    float* dinv = (float*)(xb + (size_t)n * 64);         // [2n]
    float* sums = dinv + n2;                             // [8][1024] replicas
    unsigned* wpk = (unsigned*)(sums + 8192);            // [36864]
    unsigned short* csr = (unsigned short*)(wpk + 36864);// [E2] u16
    int* rowptr = (int*)(csr + (size_t)E2);              // [2n+1]
    int* bcnt   = rowptr + (n2 + 1);                     // [512]
    int* bstart = bcnt + 512;                            // [NB+1]
    unsigned short* t0b = Tb;
    unsigned* binned = (unsigned*)comb;                  // [NB*BSTRIDE] = 16MB <= 25.6MB
    unsigned* w0T0 = wpk + 0,    *w0T1 = wpk + 2048;
    unsigned* w1T0 = wpk + 4096, *w1T1 = wpk + 8192;
    unsigned* rT0  = wpk + 12288,*rT1  = wpk + 16384;
    unsigned* fT   = wpk + 20480;

    // --- prep (weights + zeroing + xb) + CSR build ---
    prep_kernel<<<cdiv(n64, 256), 256, 0, stream>>>(w0_s0, w0_s1, w1_s0, w1_s1,
                                                    res1_s0, res1_s1, fc1_w, x,
                                                    wpk, bcnt, sums, xb, n64);
    kC_bin<<<cdiv(E2, 8192), 512, 0, stream>>>(ei0, ei1, bcnt, binned, E, n);
    kB_scan<<<1, 256, 0, stream>>>(bcnt, bstart, NB);
    kD_build<<<NB, 512, 0, stream>>>(binned, bstart, rowptr, dinv, csr, n2, NB);

    // --- layer 0: weighted gather(xb, shared) -> MFMA @W0 (+stats) -> apply0 ---
    gatherw_kernel<<<cdiv(n2 * 8, 256), 256, 0, stream>>>(rowptr, csr, xb, 0, dinv, Gb, n, n2);
    mfma_gemmb<64><<<2 * BPS, 256, 0, stream>>>(Gb, w0T0, w0T1, t0b, sums, 512, n);
    apply0_kernel<<<2 * n64 / 256, 256, 0, stream>>>(t0b, x, sums, 512, bn_g0, bn_b0,
                                                     h1b, n64, n);

    // --- layer 1: weighted gather(h1b) -> MFMA @W1 (+stats) -> apply1 ---
    gatherw_kernel<<<cdiv(n2 * 8, 256), 256, 0, stream>>>(rowptr, csr, h1b, (size_t)n * 64,
                                                          dinv, Gb, n, n2);
    mfma_gemmb<128><<<2 * BPS, 256, 0, stream>>>(Gb, w1T0, w1T1, Tb, sums, 0, n);
    mfma_apply1<<<2 * BPS, 256, 0, stream>>>(h1b, Tb, rT0, rT1, sums, bn_g1, bn_b1,
                                             comb, n);

    // --- fused head + fc2 + softmax ---
    mfma_head_fc2<<<BPS, 256, 0, stream>>>(comb, fT, fc1_b, fc2_w, fc2_b, out, n);
}

// Round 15
// 389.731 us; speedup vs baseline: 1.0475x; 1.0249x over previous
//
#include <hip/hip_runtime.h>
#include <hip/hip_bf16.h>
#include <math.h>

// ---------------------------------------------------------------------------
// DriverGeneGNN: 2-slice GCN (64->64->128) + BN + residual + MLP head.
// N=50000, E=1600000. fp32 accumulate, bf16 operands + bf16 intermediates.
// R15 = best-of(R12,R14): unweighted gather on PRESCALED tables (R12's
//      36-VGPR kernel, 43us measured; R14's per-edge weighting cost 20 VGPR
//      and 10us, and its shared-table FETCH win never materialized) + R14's
//      inline-BN apply prologues (no bnfinal dispatches) + fused head/fc2.
// CSR build (R12): kC bins into fixed-stride bucket segments, kB scan, kD.
// GEMMs (R12): de-staged MFMA vs L2-resident packed W^T, fused BN stats
//      into 8-way replicated sums.
// MFMA frag layouts (HW-verified): A[m=lane&15][k=(lane>>4)*8+j],
//     B[k][n=lane&15], C/D col=lane&15 row=(lane>>4)*4+reg.
// Conv biases cancel in BN -> skipped.
// ---------------------------------------------------------------------------

typedef short v8s __attribute__((ext_vector_type(8)));
typedef float f32x4 __attribute__((ext_vector_type(4)));

#define BSTRIDE 10240  // u32 slots per 256-col bucket segment (mean 8184)

__device__ __forceinline__ float sanf(float v) {
    if (v != v) return 0.f;
    if (isinf(v)) return v > 0.f ? 100.f : -100.f;
    return v;
}

__device__ __forceinline__ unsigned short bf16of(float v) {
    __hip_bfloat16 h = __float2bfloat16(v);
    return *(unsigned short*)&h;
}
__device__ __forceinline__ unsigned pack2(float lo, float hi) {
    return (unsigned)bf16of(lo) | ((unsigned)bf16of(hi) << 16);
}
__device__ __forceinline__ float uflo(unsigned u) { return __uint_as_float(u << 16); }
__device__ __forceinline__ float ufhi(unsigned u) { return __uint_as_float(u & 0xFFFF0000u); }
__device__ __forceinline__ float fofbf16(unsigned short u) {
    return __uint_as_float(((unsigned)u) << 16);
}

// --- prep: pack weights (W^T bf16-pairs), zero bcnt/sums --------------------
__device__ __forceinline__ void packone(const float* __restrict__ src, unsigned* __restrict__ dst,
                                        int L, int Khalf, int F) {
    int c = L / Khalf, kp = L - c * Khalf;
    dst[L] = pack2(src[(2 * kp) * F + c], src[(2 * kp + 1) * F + c]);
}

__global__ __launch_bounds__(256) void prep_kernel(const float* __restrict__ w0_0,
                                                   const float* __restrict__ w0_1,
                                                   const float* __restrict__ w1_0,
                                                   const float* __restrict__ w1_1,
                                                   const float* __restrict__ r_0,
                                                   const float* __restrict__ r_1,
                                                   const float* __restrict__ fc1,
                                                   unsigned* __restrict__ wpk,
                                                   int* __restrict__ bcnt,
                                                   float* __restrict__ sums) {
    int gid = blockIdx.x * 256 + threadIdx.x;
    if (gid < 512) bcnt[gid] = 0;
    if (gid < 8192) sums[gid] = 0.f;
    if (gid < 2048)       packone(w0_0, wpk + 0,     gid - 0,     32, 64);
    else if (gid < 4096)  packone(w0_1, wpk + 2048,  gid - 2048,  32, 64);
    else if (gid < 8192)  packone(w1_0, wpk + 4096,  gid - 4096,  32, 128);
    else if (gid < 12288) packone(w1_1, wpk + 8192,  gid - 8192,  32, 128);
    else if (gid < 16384) packone(r_0,  wpk + 12288, gid - 12288, 32, 128);
    else if (gid < 20480) packone(r_1,  wpk + 16384, gid - 16384, 32, 128);
    else if (gid < 36864) packone(fc1,  wpk + 20480, gid - 20480, 128, 128);
}

// --- CSR build (R12) ---------------------------------------------------------

__global__ __launch_bounds__(512) void kC_bin(const int* __restrict__ ei0,
                                              const int* __restrict__ ei1,
                                              int* __restrict__ bcnt,
                                              unsigned* __restrict__ binned,
                                              int E, int n) {
    __shared__ int cnt[512];
    __shared__ int base[512];
    int t = threadIdx.x;
    cnt[t] = 0;
    int E2 = 2 * E;
    int e0 = blockIdx.x * 8192;
    unsigned pk[16];
    int bk[16];
    __syncthreads();
#pragma unroll
    for (int j = 0; j < 16; ++j) {
        int ge = e0 + t + j * 512;
        bk[j] = -1;
        if (ge < E2) {
            int slice = ge >= E;
            const int* ei = slice ? ei1 : ei0;
            int e = ge - slice * E;
            int col = ei[E + e], row = ei[e];
            int gcol = slice * n + col;
            bk[j] = gcol >> 8;
            pk[j] = (unsigned)row | (((unsigned)gcol & 255u) << 16);
            atomicAdd(&cnt[bk[j]], 1);
        }
    }
    __syncthreads();
    {
        int c = cnt[t];
        base[t] = c ? atomicAdd(&bcnt[t], c) : 0;
    }
    __syncthreads();
    cnt[t] = 0;
    __syncthreads();
#pragma unroll
    for (int j = 0; j < 16; ++j) {
        if (bk[j] >= 0) {
            int loc = atomicAdd(&cnt[bk[j]], 1);
            int off = base[bk[j]] + loc;
            if (off < BSTRIDE) binned[(size_t)bk[j] * BSTRIDE + off] = pk[j];
        }
    }
}

__global__ __launch_bounds__(256) void kB_scan(const int* __restrict__ bcnt,
                                               int* __restrict__ bstart, int NB) {
    __shared__ int tmp[256];
    int t = threadIdx.x, carry = 0;
    for (int bse = 0; bse < NB; bse += 256) {
        int i = bse + t;
        int v = (i < NB) ? bcnt[i] : 0;
        tmp[t] = v;
        __syncthreads();
        for (int off = 1; off < 256; off <<= 1) {
            int u = (t >= off) ? tmp[t - off] : 0;
            __syncthreads();
            tmp[t] += u;
            __syncthreads();
        }
        if (i < NB) bstart[i] = tmp[t] - v + carry;
        carry += tmp[255];
        __syncthreads();
    }
    if (t == 0) bstart[NB] = carry;
}

__global__ __launch_bounds__(512) void kD_build(const unsigned* __restrict__ binned,
                                                const int* __restrict__ bstart,
                                                int* __restrict__ rowptr,
                                                float* __restrict__ dinv,
                                                unsigned short* __restrict__ csr,
                                                int n2, int NB) {
    __shared__ int cnt[256];
    __shared__ int scn[256];
    __shared__ int cur[256];
    int b = blockIdx.x, t = threadIdx.x;
    int s = bstart[b], e = bstart[b + 1];
    int m = e - s;
    const unsigned* seg = binned + (size_t)b * BSTRIDE;
    if (t < 256) cnt[t] = 0;
    __syncthreads();
    for (int i = t; i < m; i += 512) atomicAdd(&cnt[(seg[i] >> 16) & 255], 1);
    __syncthreads();
    int v = (t < 256) ? cnt[t] : 0;
    if (t < 256) scn[t] = v;
    __syncthreads();
    for (int off = 1; off < 256; off <<= 1) {
        int u = (t < 256 && t >= off) ? scn[t - off] : 0;
        __syncthreads();
        if (t < 256) scn[t] += u;
        __syncthreads();
    }
    if (t < 256) {
        int excl = scn[t] - v;
        int gcol = b * 256 + t;
        if (gcol < n2) {
            rowptr[gcol] = s + excl;
            dinv[gcol] = v > 0 ? rsqrtf((float)v) : 0.f;
        }
        cur[t] = excl;
    }
    __syncthreads();
    for (int i = t; i < m; i += 512) {
        unsigned p = seg[i];
        int cl = (p >> 16) & 255;
        int pos = s + atomicAdd(&cur[cl], 1);
        csr[pos] = (unsigned short)(p & 0xFFFFu);
    }
    if (b == 0 && t == 0) rowptr[n2] = bstart[NB];
}

// --- gather path (prescaled bf16 tables; 8 lanes/node, 8 loads in flight) ---

// xsb[slice][row] = bf16(dinv[slice][row] * x[row])
__global__ __launch_bounds__(256) void prescale_bf(const float* __restrict__ x,
                                                   const float* __restrict__ dinv,
                                                   unsigned short* __restrict__ xsb,
                                                   int n64, int n) {
    int i = blockIdx.x * 256 + threadIdx.x;
    if (i >= n64) return;
    int row = i >> 6;
    float v = x[i];
    xsb[i] = bf16of(v * dinv[row]);
    xsb[n64 + i] = bf16of(v * dinv[n + row]);
}

__global__ __launch_bounds__(256) void gatherbf_kernel(const int* __restrict__ rowptr,
                                                       const unsigned short* __restrict__ csr,
                                                       const unsigned short* __restrict__ m,
                                                       const float* __restrict__ dinv,
                                                       unsigned short* __restrict__ outb,
                                                       int n, int n2) {
    int gid = blockIdx.x * 256 + threadIdx.x;
    int node = gid >> 3;
    if (node >= n2) return;
    int l = threadIdx.x & 7;
    const unsigned short* mb = m + (size_t)((node >= n) ? n : 0) * 64;
    int s = rowptr[node], e = rowptr[node + 1];
    float a0 = 0.f, a1 = 0.f, a2 = 0.f, a3 = 0.f, a4 = 0.f, a5 = 0.f, a6 = 0.f, a7 = 0.f;
    int b = s;
    for (; b + 8 <= e; b += 8) {
        int idx = csr[b + l];
        uint4 u[8];
#pragma unroll
        for (int j = 0; j < 8; ++j) {
            int r = __shfl(idx, j, 8);
            u[j] = *(const uint4*)&m[(size_t)(((node >= n) ? n : 0) + r) * 64 + l * 8];
        }
#pragma unroll
        for (int j = 0; j < 8; ++j) {
            a0 += uflo(u[j].x); a1 += ufhi(u[j].x);
            a2 += uflo(u[j].y); a3 += ufhi(u[j].y);
            a4 += uflo(u[j].z); a5 += ufhi(u[j].z);
            a6 += uflo(u[j].w); a7 += ufhi(u[j].w);
        }
    }
    if (b < e) {
        int cntn = e - b;
        int idx = (b + l < e) ? (int)csr[b + l] : 0;
        for (int j = 0; j < cntn; ++j) {
            int r = __shfl(idx, j, 8);
            uint4 u = *(const uint4*)&mb[(size_t)r * 64 + l * 8];
            a0 += uflo(u.x); a1 += ufhi(u.x);
            a2 += uflo(u.y); a3 += ufhi(u.y);
            a4 += uflo(u.z); a5 += ufhi(u.z);
            a6 += uflo(u.w); a7 += ufhi(u.w);
        }
    }
    float d = dinv[node];
    uint4 o;
    o.x = pack2(a0 * d, a1 * d);
    o.y = pack2(a2 * d, a3 * d);
    o.z = pack2(a4 * d, a5 * d);
    o.w = pack2(a6 * d, a7 * d);
    *(uint4*)&outb[(size_t)node * 64 + l * 8] = o;
}

// --- de-staged MFMA GEMMs (R12) ---------------------------------------------

template <int F>
__global__ __launch_bounds__(256) void mfma_gemmb(const unsigned short* __restrict__ Ab,
                                                  const unsigned* __restrict__ WT0,
                                                  const unsigned* __restrict__ WT1,
                                                  unsigned short* __restrict__ Cb,
                                                  float* __restrict__ sums_base,
                                                  int roff, int n) {
    constexpr int NC = F / 16;
    __shared__ float ls[2 * F];
    int BPS = (n + 63) >> 6;
    int slice = blockIdx.x >= BPS;
    int sb = blockIdx.x - slice * BPS;
    const unsigned* WT = slice ? WT1 : WT0;
    int row0 = slice * n + sb * 64;
    int rows = min(64, n - sb * 64);
    for (int i = threadIdx.x; i < 2 * F; i += 256) ls[i] = 0.f;
    int w = threadIdx.x >> 6, lane = threadIdx.x & 63, q = lane >> 4, ln = lane & 15;
    const unsigned* A32 = (const unsigned*)Ab;
    size_t arow = (size_t)(row0 + 16 * w + ln) * 32;
    v8s af0 = *(const v8s*)&A32[arow + q * 4];
    v8s af1 = *(const v8s*)&A32[arow + 16 + q * 4];
    f32x4 acc[NC];
#pragma unroll
    for (int ct = 0; ct < NC; ++ct) acc[ct] = {0.f, 0.f, 0.f, 0.f};
#pragma unroll
    for (int ct = 0; ct < NC; ++ct) {
        v8s b0 = *(const v8s*)&WT[(ct * 16 + ln) * 32 + q * 4];
        v8s b1 = *(const v8s*)&WT[(ct * 16 + ln) * 32 + 16 + q * 4];
        acc[ct] = __builtin_amdgcn_mfma_f32_16x16x32_bf16(af0, b0, acc[ct], 0, 0, 0);
        acc[ct] = __builtin_amdgcn_mfma_f32_16x16x32_bf16(af1, b1, acc[ct], 0, 0, 0);
    }
    __syncthreads();  // ls zero-init visible
#pragma unroll
    for (int ct = 0; ct < NC; ++ct) {
        float s1 = 0.f, s2 = 0.f;
#pragma unroll
        for (int i = 0; i < 4; ++i) {
            int r = 16 * w + q * 4 + i;
            if (r < rows) {
                float v = acc[ct][i];
                Cb[(size_t)(row0 + r) * F + ct * 16 + ln] = bf16of(v);
                s1 += v;
                s2 += v * v;
            }
        }
        s1 += __shfl_xor(s1, 16); s1 += __shfl_xor(s1, 32);
        s2 += __shfl_xor(s2, 16); s2 += __shfl_xor(s2, 32);
        if (q == 0) {
            atomicAdd(&ls[ct * 16 + ln], s1);
            atomicAdd(&ls[F + ct * 16 + ln], s2);
        }
    }
    __syncthreads();
    if (threadIdx.x < F) {
        float* dst = sums_base + (blockIdx.x & 7) * 1024 + roff + slice * 2 * F;
        unsafeAtomicAdd(&dst[threadIdx.x], ls[threadIdx.x]);
        unsafeAtomicAdd(&dst[F + threadIdx.x], ls[F + threadIdx.x]);
    }
}

// --- pointwise / epilogue kernels (BN-final inline from replicated sums) ----

// h1b = bf16(san(relu(bn(t0b)) + x)); h1sb = bf16(dinv * h1)
__global__ __launch_bounds__(256) void apply0_kernel(const unsigned short* __restrict__ t0b,
                                                     const float* __restrict__ x,
                                                     const float* __restrict__ sums_base,
                                                     int roff,
                                                     const float* __restrict__ g,
                                                     const float* __restrict__ be,
                                                     const float* __restrict__ dinv,
                                                     unsigned short* __restrict__ h1b,
                                                     unsigned short* __restrict__ h1sb,
                                                     int n64, int n) {
    __shared__ float sc[128];
    int i0 = blockIdx.x * 256;
    int slice = i0 >= n64;
    int t = threadIdx.x;
    if (t < 64) {
        float s1 = 0.f, s2 = 0.f;
#pragma unroll
        for (int r = 0; r < 8; ++r) {
            const float* src = sums_base + r * 1024 + roff + slice * 128;
            s1 += src[t];
            s2 += src[64 + t];
        }
        float inv_n = 1.0f / (float)n;
        float mu = s1 * inv_n;
        float var = fmaxf(s2 * inv_n - mu * mu, 0.f);
        float scale = g[t] * rsqrtf(var + 1e-5f);
        sc[t] = scale;
        sc[64 + t] = be[t] - mu * scale;
    }
    __syncthreads();
    int i = i0 + t;
    int f = i & 63;
    float v = fmaf(fofbf16(t0b[i]), sc[f], sc[64 + f]);
    v = fmaxf(v, 0.f) + x[i - slice * n64];
    v = sanf(v);
    h1b[i] = bf16of(v);
    h1sb[i] = bf16of(v * dinv[i >> 6]);
}

// comb[lrow, slice*128 + c] (bf16) = san(bn(Tb) + h1b @ res_slice)
__global__ __launch_bounds__(256) void mfma_apply1(const unsigned short* __restrict__ h1b,
                                                   const unsigned short* __restrict__ Tb,
                                                   const unsigned* __restrict__ RT0,
                                                   const unsigned* __restrict__ RT1,
                                                   const float* __restrict__ sums_base,
                                                   const float* __restrict__ g,
                                                   const float* __restrict__ be,
                                                   unsigned short* __restrict__ comb, int n) {
    __shared__ float sc[256];
    int BPS = (n + 63) >> 6;
    int slice = blockIdx.x >= BPS;
    int sb = blockIdx.x - slice * BPS;
    int row0 = slice * n + sb * 64;
    int rows = min(64, n - sb * 64);
    int t = threadIdx.x;
    if (t < 128) {
        float s1 = 0.f, s2 = 0.f;
#pragma unroll
        for (int r = 0; r < 8; ++r) {
            const float* src = sums_base + r * 1024 + slice * 256;
            s1 += src[t];
            s2 += src[128 + t];
        }
        float inv_n = 1.0f / (float)n;
        float mu = s1 * inv_n;
        float var = fmaxf(s2 * inv_n - mu * mu, 0.f);
        float scale = g[t] * rsqrtf(var + 1e-5f);
        sc[t] = scale;
        sc[128 + t] = be[t] - mu * scale;
    }
    __syncthreads();
    const unsigned* WT = slice ? RT1 : RT0;
    int w = t >> 6, lane = t & 63, q = lane >> 4, ln = lane & 15;
    const unsigned* A32 = (const unsigned*)h1b;
    size_t arow = (size_t)(row0 + 16 * w + ln) * 32;
    v8s af0 = *(const v8s*)&A32[arow + q * 4];
    v8s af1 = *(const v8s*)&A32[arow + 16 + q * 4];
    f32x4 acc[8];
#pragma unroll
    for (int ct = 0; ct < 8; ++ct) acc[ct] = {0.f, 0.f, 0.f, 0.f};
#pragma unroll
    for (int ct = 0; ct < 8; ++ct) {
        v8s b0 = *(const v8s*)&WT[(ct * 16 + ln) * 32 + q * 4];
        v8s b1 = *(const v8s*)&WT[(ct * 16 + ln) * 32 + 16 + q * 4];
        acc[ct] = __builtin_amdgcn_mfma_f32_16x16x32_bf16(af0, b0, acc[ct], 0, 0, 0);
        acc[ct] = __builtin_amdgcn_mfma_f32_16x16x32_bf16(af1, b1, acc[ct], 0, 0, 0);
    }
#pragma unroll
    for (int ct = 0; ct < 8; ++ct) {
        int c = ct * 16 + ln;
        float scale = sc[c], shift = sc[128 + c];
#pragma unroll
        for (int i = 0; i < 4; ++i) {
            int r = 16 * w + q * 4 + i;
            if (r >= rows) continue;
            int row = row0 + r;
            float tv = fofbf16(Tb[(size_t)row * 128 + c]);
            float o = sanf(fmaf(tv, scale, shift) + acc[ct][i]);
            comb[(size_t)(row - slice * n) * 256 + slice * 128 + c] = bf16of(o);
        }
    }
}

// fused head: h = relu(comb @ fc1 + b1); logits = h @ fc2 + b2; softmax.
__global__ __launch_bounds__(256) void mfma_head_fc2(const unsigned short* __restrict__ comb,
                                                     const unsigned* __restrict__ FT,
                                                     const float* __restrict__ bias,
                                                     const float* __restrict__ w2,
                                                     const float* __restrict__ b2,
                                                     float* __restrict__ out, int n) {
    int row0 = blockIdx.x * 64;
    int rows = min(64, n - row0);
    int w = threadIdx.x >> 6, lane = threadIdx.x & 63, q = lane >> 4, ln = lane & 15;
    const unsigned* A32 = (const unsigned*)comb;
    size_t arow = (size_t)(row0 + 16 * w + ln) * 128;
    f32x4 acc[8];
#pragma unroll
    for (int ct = 0; ct < 8; ++ct) acc[ct] = {0.f, 0.f, 0.f, 0.f};
#pragma unroll
    for (int kt = 0; kt < 4; ++kt) {
        v8s af0 = *(const v8s*)&A32[arow + kt * 32 + q * 4];
        v8s af1 = *(const v8s*)&A32[arow + kt * 32 + 16 + q * 4];
#pragma unroll
        for (int ct = 0; ct < 8; ++ct) {
            v8s b0 = *(const v8s*)&FT[(ct * 16 + ln) * 128 + kt * 32 + q * 4];
            v8s b1 = *(const v8s*)&FT[(ct * 16 + ln) * 128 + kt * 32 + 16 + q * 4];
            acc[ct] = __builtin_amdgcn_mfma_f32_16x16x32_bf16(af0, b0, acc[ct], 0, 0, 0);
            acc[ct] = __builtin_amdgcn_mfma_f32_16x16x32_bf16(af1, b1, acc[ct], 0, 0, 0);
        }
    }
    float p0[4] = {0.f, 0.f, 0.f, 0.f}, p1[4] = {0.f, 0.f, 0.f, 0.f};
#pragma unroll
    for (int ct = 0; ct < 8; ++ct) {
        int c = ct * 16 + ln;
        float bi = bias[c];
        float w20 = w2[c * 2], w21 = w2[c * 2 + 1];
#pragma unroll
        for (int i = 0; i < 4; ++i) {
            float h = fmaxf(acc[ct][i] + bi, 0.f);
            p0[i] = fmaf(h, w20, p0[i]);
            p1[i] = fmaf(h, w21, p1[i]);
        }
    }
#pragma unroll
    for (int i = 0; i < 4; ++i) {
#pragma unroll
        for (int msk = 1; msk < 16; msk <<= 1) {
            p0[i] += __shfl_xor(p0[i], msk);
            p1[i] += __shfl_xor(p1[i], msk);
        }
    }
    if (ln == 0) {
        float bb0 = b2[0], bb1 = b2[1];
#pragma unroll
        for (int i = 0; i < 4; ++i) {
            int r = 16 * w + q * 4 + i;
            if (r >= rows) continue;
            int R = row0 + r;
            float l0 = p0[i] + bb0, l1 = p1[i] + bb1;
            float mx = fmaxf(l0, l1);
            float e0 = expf(l0 - mx), e1 = expf(l1 - mx);
            float inv = 1.0f / (e0 + e1);
            out[(size_t)R * 2] = l0;
            out[(size_t)R * 2 + 1] = l1;
            out[(size_t)2 * n + R * 2] = e0 * inv;
            out[(size_t)2 * n + R * 2 + 1] = e1 * inv;
        }
    }
}

static inline int cdiv(int a, int b) { return (a + b - 1) / b; }

extern "C" void kernel_launch(void* const* d_in, const int* in_sizes, int n_in,
                              void* d_out, int out_size, void* d_ws, size_t ws_size,
                              hipStream_t stream) {
    const float* x       = (const float*)d_in[0];
    const int*   ei0     = (const int*)d_in[1];
    const int*   ei1     = (const int*)d_in[2];
    const float* w0_s0   = (const float*)d_in[3];
    const float* w1_s0   = (const float*)d_in[5];
    const float* res1_s0 = (const float*)d_in[7];
    const float* w0_s1   = (const float*)d_in[8];
    const float* w1_s1   = (const float*)d_in[10];
    const float* res1_s1 = (const float*)d_in[12];
    const float* bn_g0   = (const float*)d_in[13];
    const float* bn_b0   = (const float*)d_in[14];
    const float* bn_g1   = (const float*)d_in[15];
    const float* bn_b1   = (const float*)d_in[16];
    const float* fc1_w   = (const float*)d_in[17];
    const float* fc1_b   = (const float*)d_in[18];
    const float* fc2_w   = (const float*)d_in[19];
    const float* fc2_b   = (const float*)d_in[20];
    float* out = (float*)d_out;

    int n = in_sizes[0] / 64;   // 50000
    int E = in_sizes[1] / 2;    // 1600000
    int n2 = 2 * n, E2 = 2 * E;
    int n64 = n * 64;
    int NB = cdiv(n2, 256);     // 391 buckets (256 cols each)
    int BPS = cdiv(n, 64);      // 782 row-tiles per slice

    // workspace layout (binned overlays comb; t0b overlays Tb):
    unsigned short* Tb   = (unsigned short*)d_ws;        // [2n*128] (t0b = first 2n*64)
    unsigned short* h1b  = Tb + (size_t)n2 * 128;        // [2n*64]
    unsigned short* h1sb = h1b + (size_t)n2 * 64;        // [2n*64]
    unsigned short* comb = h1sb + (size_t)n2 * 64;       // [n*256]
    unsigned short* Gb   = comb + (size_t)n * 256;       // [2n*64]
    unsigned short* xsb  = Gb + (size_t)n2 * 64;         // [2n*64] prescaled tables
    float* dinv = (float*)(xsb + (size_t)n2 * 64);       // [2n]
    float* sums = dinv + n2;                             // [8][1024] replicas
    unsigned* wpk = (unsigned*)(sums + 8192);            // [36864]
    unsigned short* csr = (unsigned short*)(wpk + 36864);// [E2] u16
    int* rowptr = (int*)(csr + (size_t)E2);              // [2n+1]
    int* bcnt   = rowptr + (n2 + 1);                     // [512]
    int* bstart = bcnt + 512;                            // [NB+1]
    unsigned short* t0b = Tb;
    unsigned* binned = (unsigned*)comb;                  // [NB*BSTRIDE] = 16MB <= 25.6MB
    unsigned* w0T0 = wpk + 0,    *w0T1 = wpk + 2048;
    unsigned* w1T0 = wpk + 4096, *w1T1 = wpk + 8192;
    unsigned* rT0  = wpk + 12288,*rT1  = wpk + 16384;
    unsigned* fT   = wpk + 20480;

    // --- prep (weights + zeroing) + CSR build ---
    prep_kernel<<<144, 256, 0, stream>>>(w0_s0, w0_s1, w1_s0, w1_s1,
                                         res1_s0, res1_s1, fc1_w, wpk, bcnt, sums);
    kC_bin<<<cdiv(E2, 8192), 512, 0, stream>>>(ei0, ei1, bcnt, binned, E, n);
    kB_scan<<<1, 256, 0, stream>>>(bcnt, bstart, NB);
    kD_build<<<NB, 512, 0, stream>>>(binned, bstart, rowptr, dinv, csr, n2, NB);

    // --- layer 0: prescale -> gather(xsb) -> MFMA @W0 (+stats) -> apply0 ---
    prescale_bf<<<cdiv(n64, 256), 256, 0, stream>>>(x, dinv, xsb, n64, n);
    gatherbf_kernel<<<cdiv(n2 * 8, 256), 256, 0, stream>>>(rowptr, csr, xsb, dinv, Gb, n, n2);
    mfma_gemmb<64><<<2 * BPS, 256, 0, stream>>>(Gb, w0T0, w0T1, t0b, sums, 512, n);
    apply0_kernel<<<2 * n64 / 256, 256, 0, stream>>>(t0b, x, sums, 512, bn_g0, bn_b0,
                                                     dinv, h1b, h1sb, n64, n);

    // --- layer 1: gather(h1sb) -> MFMA @W1 (+stats) -> apply1 ---
    gatherbf_kernel<<<cdiv(n2 * 8, 256), 256, 0, stream>>>(rowptr, csr, h1sb, dinv, Gb, n, n2);
    mfma_gemmb<128><<<2 * BPS, 256, 0, stream>>>(Gb, w1T0, w1T1, Tb, sums, 0, n);
    mfma_apply1<<<2 * BPS, 256, 0, stream>>>(h1b, Tb, rT0, rT1, sums, bn_g1, bn_b1,
                                             comb, n);

    // --- fused head + fc2 + softmax ---
    mfma_head_fc2<<<BPS, 256, 0, stream>>>(comb, fT, fc1_b, fc2_w, fc2_b, out, n);
}